// Round 9
// baseline (106.518 us; speedup 1.0000x reference)
//
#include <hip/hip_runtime.h>

// 8-level sym8 wavelet packet transform, B=128 rows of L0=65536, f32.
// 3 fused kernels: F01 (levels 0-1), F23 (levels 2-3), F47 (levels 4-7).
// Lengths: 65536->32775->16395->8205->4110->2062->1038->526->270.
// Interleaved layout (R6 structure), NO=4: each group computes 4 consecutive
// outputs for both filters from a 24-float window = 6x ds_read_b128 (16B
// aligned: margins are 16 floats, window base 8u, writes at 16+4*u), 128 FMA,
// one float4 write. Pair kernels: virtual A-tile (reflect at build/edge
// recompute). Quad: 16-float mirrored margins on every subrow ext buffer.

#define BT 512

// fl[t] = dec_lo[15-t]  (flipped low-pass, cross-correlation form)
__device__ __constant__ float FL[16] = {
     0.0018899503327594609f, -0.0003029205147213668f, -0.01495225833704823f,
     0.003808752013890615f,   0.049137179673607506f,  -0.027219029917056003f,
    -0.05194583810770904f,    0.3644418948353314f,     0.7771857517005235f,
     0.4813596512583722f,    -0.061273359067658524f,  -0.1432942383508097f,
     0.007607487324917605f,   0.03169508781149298f,   -0.0005421323317911481f,
    -0.0033824159510061256f
};

// fh[t] = dec_hi[15-t] = (t odd ? +1 : -1) * dec_lo[t]
__device__ __constant__ float FH[16] = {
     0.0033824159510061256f, -0.0005421323317911481f, -0.03169508781149298f,
     0.007607487324917605f,   0.1432942383508097f,    -0.061273359067658524f,
    -0.4813596512583722f,     0.7771857517005235f,    -0.3644418948353314f,
    -0.05194583810770904f,    0.027219029917056003f,   0.049137179673607506f,
    -0.003808752013890615f,  -0.01495225833704823f,    0.0003029205147213668f,
     0.0018899503327594609f
};

__device__ __forceinline__ int reflect(int q, int L) {
    q = (q < 0) ? -q : q;
    return (q >= L) ? (2 * L - 2 - q) : q;
}

// 24-float window: 6 x ds_read_b128 (idx0 must be a multiple of 4).
__device__ __forceinline__ void read24(const float* __restrict__ lds, int idx0,
                                       float w[24]) {
#pragma unroll
    for (int k = 0; k < 6; ++k) {
        const float4 v = *reinterpret_cast<const float4*>(&lds[idx0 + 4 * k]);
        w[4 * k] = v.x; w[4 * k + 1] = v.y; w[4 * k + 2] = v.z; w[4 * k + 3] = v.w;
    }
}

// 4 consecutive outputs (both filters). Tap for output d: w[OFF + 2d + t].
template <int OFF>
__device__ __forceinline__ void conv4(const float w[24], float lo[4], float hi[4]) {
#pragma unroll
    for (int d = 0; d < 4; ++d) { lo[d] = 0.f; hi[d] = 0.f; }
#pragma unroll
    for (int t = 0; t < 16; ++t) {
        const float cl = FL[t], ch = FH[t];
#pragma unroll
        for (int d = 0; d < 4; ++d) {
            const float v = w[OFF + 2 * d + t];
            lo[d] = fmaf(v, cl, lo[d]);
            hi[d] = fmaf(v, ch, hi[d]);
        }
    }
}

// Scalar conv: window starts at lds[r] (any alignment).
__device__ __forceinline__ void conv1(const float* __restrict__ lds, int r,
                                      float& lo, float& hi) {
    lo = hi = 0.f;
#pragma unroll
    for (int t = 0; t < 16; ++t) {
        const float v = lds[r + t];
        lo = fmaf(v, FL[t], lo);
        hi = fmaf(v, FH[t], hi);
    }
}

// ---------------- Fused two-level kernel (levels k, k+1) ----------------
template <int LIN, int LA, int LB, int SIN, int SOUT, int MB>
__global__ __launch_bounds__(BT, 8) void dwt_pair4(
    const float* __restrict__ x, float* __restrict__ y) {
    constexpr int WA  = 2 * MB + 14;            // virtual A-tile width
    constexpr int WAp = 2 * MB + 16;            // stride (covers B read 8v+24)
    constexpr int GA  = (WA + 3) / 4;           // A groups
    constexpr int GB  = MB / 4;                 // B groups per subband
    constexpr int WX  = 2 * WA + 14;            // x coverage
    constexpr int XSp = ((8 * (GA - 1) + 24) + 3) & ~3;
    __shared__ __align__(16) float xs[XSp];
    __shared__ __align__(16) float as[2 * WAp];

    const int seg  = blockIdx.x;
    const int n    = blockIdx.y;
    const int b0   = seg * MB;
    const int a_lo = 2 * b0 - 14;               // virtual A start
    const int px0  = 2 * a_lo - 14;             // x position of xs[0] (even)
    const float* row = x + (size_t)n * (size_t)SIN;

    // ---- x-tile fill ----
    if (px0 >= 0 && px0 + WX <= LIN) {
        const float2* rp = reinterpret_cast<const float2*>(row + px0);
        for (int h = threadIdx.x; h < WX / 2; h += BT)
            *reinterpret_cast<float2*>(&xs[2 * h]) = rp[h];
    } else {
        for (int p = threadIdx.x; p < WX; p += BT)
            xs[p] = row[reflect(px0 + p, LIN)];
    }
    __syncthreads();

    // ---- A-phase: virtual positions a_lo + s, s in [0, WA) ----
    const int jbmax = ((b0 + MB < LB) ? (b0 + MB) : LB) - 1;
    const int smax  = 2 * (jbmax - b0) + 15;
    for (int g = threadIdx.x; g < GA; g += BT) {
        const int s0 = 4 * g;
        if (s0 > smax) continue;
        const int a0 = a_lo + s0;
        float lo[4], hi[4];
        if (a0 >= 0 && a0 + 3 < LA) {
            float w[24];
            read24(xs, 8 * g, w);               // taps: w[2d + t]
            conv4<0>(w, lo, hi);
        } else {
#pragma unroll
            for (int d = 0; d < 4; ++d) {
                const int s2 = reflect(a0 + d, LA) - a_lo;  // in [0, WA)
                conv1(xs, 2 * s2, lo[d], hi[d]);
            }
        }
        if (s0 + 3 < WA) {
            *reinterpret_cast<float4*>(&as[s0])       = make_float4(lo[0], lo[1], lo[2], lo[3]);
            *reinterpret_cast<float4*>(&as[WAp + s0]) = make_float4(hi[0], hi[1], hi[2], hi[3]);
        } else {                                // WA % 4 == 2: 2 valid
            *reinterpret_cast<float2*>(&as[s0])       = make_float2(lo[0], lo[1]);
            *reinterpret_cast<float2*>(&as[WAp + s0]) = make_float2(hi[0], hi[1]);
        }
    }
    __syncthreads();

    // ---- B-phase ----
    for (int g = threadIdx.x; g < 2 * GB; g += BT) {
        const int sA  = (g >= GB) ? 1 : 0;
        const int v   = g - sA * GB;
        const int jb0 = b0 + 4 * v;
        if (jb0 >= LB) continue;
        float w[24];
        read24(as, sA * WAp + 8 * v, w);        // rel = 2j - 14 - a_lo = 8v + 2d + t
        float lo[4], hi[4];
        conv4<0>(w, lo, hi);
        float* y0 = y + (size_t)(4 * n + 2 * sA) * (size_t)SOUT + (size_t)jb0;
        float* y1 = y0 + SOUT;
        if (jb0 + 3 < LB) {
            *reinterpret_cast<float4*>(y0) = make_float4(lo[0], lo[1], lo[2], lo[3]);
            *reinterpret_cast<float4*>(y1) = make_float4(hi[0], hi[1], hi[2], hi[3]);
        } else {
#pragma unroll
            for (int i = 0; i < 4; ++i)
                if (jb0 + i < LB) { y0[i] = lo[i]; y1[i] = hi[i]; }
        }
    }
}

// ---------------- Fused four-level kernel (levels 4-7) ----------------
// ext layout per subrow: [16 margin | L genuine | 16 margin/pad], stride S.
// Genuine position p lives at ext[16 + p]; taps for output j are at
// ext[2j + 2 + t] -> window base 8u (16B aligned), taps w[2 + 2d + t].
template <int L, int P, int Sin, int Sout, bool LOG>
__device__ __forceinline__ void stage4(const float* __restrict__ inb,
                                       float* __restrict__ outb,
                                       float* __restrict__ outg) {
    constexpr int LOUT = L / 2 + 7;             // even, LOUT % 4 == 2
    constexpr int GPS  = (LOUT + 3) / 4;
    for (int g = threadIdx.x; g < P * GPS; g += BT) {
        const int p  = g / GPS;                 // compile-time divisor
        const int u  = g - p * GPS;
        const int j0 = 4 * u;
        float w[24];
        read24(inb + p * Sin, 8 * u, w);
        float lo[4], hi[4];
        conv4<2>(w, lo, hi);
        if (LOG) {
            float r0[4], r1[4];
#pragma unroll
            for (int d = 0; d < 4; ++d) {
                r0[d] = __logf(fmaf(lo[d], lo[d], 1e-12f));
                r1[d] = __logf(fmaf(hi[d], hi[d], 1e-12f));
            }
            float* y0 = outg + (2 * p) * 270 + j0;
            float* y1 = y0 + 270;
            if (j0 + 3 < 270) {
                *reinterpret_cast<float4*>(y0) = make_float4(r0[0], r0[1], r0[2], r0[3]);
                *reinterpret_cast<float4*>(y1) = make_float4(r1[0], r1[1], r1[2], r1[3]);
            } else {                            // 270 % 4 == 2
                *reinterpret_cast<float2*>(y0) = make_float2(r0[0], r0[1]);
                *reinterpret_cast<float2*>(y1) = make_float2(r1[0], r1[1]);
            }
        } else {
            float* e0 = outb + (2 * p) * Sout;  // ext base, lo subrow
            float* e1 = e0 + Sout;              // ext base, hi subrow
            if (j0 + 3 < LOUT) {
                *reinterpret_cast<float4*>(&e0[16 + j0]) = make_float4(lo[0], lo[1], lo[2], lo[3]);
                *reinterpret_cast<float4*>(&e1[16 + j0]) = make_float4(hi[0], hi[1], hi[2], hi[3]);
            } else {                            // LOUT % 4 == 2: 2 valid
                *reinterpret_cast<float2*>(&e0[16 + j0]) = make_float2(lo[0], lo[1]);
                *reinterpret_cast<float2*>(&e1[16 + j0]) = make_float2(hi[0], hi[1]);
            }
            if (j0 <= 14) {                     // left margin sources j in [1,14]
#pragma unroll
                for (int d = 0; d < 4; ++d) {
                    const int j = j0 + d;
                    if (j >= 1 && j <= 14) { e0[16 - j] = lo[d]; e1[16 - j] = hi[d]; }
                }
            }
            if (j0 >= LOUT - 18) {              // right margin sources j in [LOUT-15, LOUT-2]
#pragma unroll
                for (int d = 0; d < 4; ++d) {
                    const int j = j0 + d;
                    if (j >= LOUT - 15 && j <= LOUT - 2) {
                        e0[16 + 2 * LOUT - 2 - j] = lo[d];
                        e1[16 + 2 * LOUT - 2 - j] = hi[d];
                    }
                }
            }
        }
    }
}

__global__ __launch_bounds__(BT, 8) void dwt_quad4(
    const float* __restrict__ x, float* __restrict__ y) {
    // ext strides: cover max b128 read 8*(GPS-1)+24
    constexpr int S1 = 4144, S2 = 2096, S3 = 1072, S4 = 560;
    __shared__ __align__(16) float bufA[4288];  // input ext S1 | stage2 out 4*S3
    __shared__ __align__(16) float bufB[4480];  // stage1 out 2*S2 | stage3 out 8*S4

    const int m = blockIdx.x;
    const float* row = x + (size_t)m * 4112;

    // fill input ext: bufA[16+p] = row[p], p in [0,4110)
    for (int i = threadIdx.x; i < 1027; i += BT) {
        const float4 v = *reinterpret_cast<const float4*>(row + 4 * i);
        *reinterpret_cast<float4*>(&bufA[16 + 4 * i]) = v;
    }
    {
        const int t = threadIdx.x;
        if (t < 14)                 bufA[15 - t] = row[1 + t];          // pos -(1+t)
        else if (t < 28)            bufA[16 + 4110 + (t - 14)] = row[4108 - (t - 14)];
        else if (t == 28)           bufA[16 + 4108] = row[4108];
        else if (t == 29)           bufA[16 + 4109] = row[4109];
    }
    __syncthreads();

    stage4<4110, 1, S1, S2, false>(bufA, bufB, nullptr);  // -> 2 x 2062
    __syncthreads();
    stage4<2062, 2, S2, S3, false>(bufB, bufA, nullptr);  // -> 4 x 1038
    __syncthreads();
    stage4<1038, 4, S3, S4, false>(bufA, bufB, nullptr);  // -> 8 x 526
    __syncthreads();
    stage4<526, 8, S4, 0, true>(bufB, nullptr, y + (size_t)m * 4320);   // 16 x 270
}

extern "C" void kernel_launch(void* const* d_in, const int* in_sizes, int n_in,
                              void* d_out, int out_size, void* d_ws, size_t ws_size,
                              hipStream_t stream) {
    const float* in = (const float*)d_in[0];
    float* out = (float*)d_out;
    float* wsA = (float*)d_ws;              // lev1: 512 rows, stride 16396
    float* wsB = (float*)d_ws + 8400000;    // lev3: 2048 rows, stride 4112

    // F01: 65536 -> 32775 -> 16395; MB=1028, 16 segs
    { dim3 g(16, 128); dwt_pair4<65536, 32775, 16395, 65536, 16396, 1028>
          <<<g, BT, 0, stream>>>(in, wsA); }
    // F23: 16395 -> 8205 -> 4110; MB=1028, 4 segs
    { dim3 g(4, 512);  dwt_pair4<16395, 8205, 4110, 16396, 4112, 1028>
          <<<g, BT, 0, stream>>>(wsA, wsB); }
    // F47: 4110 -> 2062 -> 1038 -> 526 -> 270(+log)
    dwt_quad4<<<2048, BT, 0, stream>>>(wsB, out);
}